// Round 12
// baseline (97.676 us; speedup 1.0000x reference)
//
#include <hip/hip_runtime.h>
#include <hip/hip_fp16.h>

typedef __fp16 h2 __attribute__((ext_vector_type(2)));

#if defined(__has_builtin)
#if __has_builtin(__builtin_amdgcn_fdot2)
#define HAVE_FDOT2 1
#endif
#endif

__device__ inline float dot2f(h2 a, h2 b, float acc) {
#ifdef HAVE_FDOT2
    return __builtin_amdgcn_fdot2(a, b, acc, false);
#else
    return acc + (float)a.x * (float)b.x + (float)a.y * (float)b.y;
#endif
}

__device__ inline float wave_sum(float v) {
#pragma unroll
    for (int off = 32; off > 0; off >>= 1) v += __shfl_down(v, off, 64);
    return v;
}

// =============== Kernel 1: prep (608 blocks x 256) — round-8 proven ===============
__global__ __launch_bounds__(256) void prep(
    const float* __restrict__ feat, const float* __restrict__ dec4,
    const float* __restrict__ gn_gap_gamma, const float* __restrict__ gn_gap_beta,
    const float* __restrict__ emb, const float* __restrict__ W_ctrl,
    float* __restrict__ partials, float* __restrict__ g_buf,
    float* __restrict__ E_ws) {
    int blk = blockIdx.x;
    int tid = threadIdx.x;
    int wid = tid >> 6, lane = tid & 63;
    if (blk < 512) {
        int grp = blk >> 3;     // b*16+g
        int chunk = blk & 7;
        const float4* base = (const float4*)(feat + (size_t)grp * 262144 + (size_t)chunk * 32768);
        float sa = 0.f, qa = 0.f, sb = 0.f, qb = 0.f;
#pragma unroll 8
        for (int i = 0; i < 16; ++i) {
            float4 v = base[i * 256 + tid];
            float4 u = base[(i + 16) * 256 + tid];
            sa += v.x + v.y + v.z + v.w;
            qa += v.x * v.x + v.y * v.y + v.z * v.z + v.w * v.w;
            sb += u.x + u.y + u.z + u.w;
            qb += u.x * u.x + u.y * u.y + u.z * u.z + u.w * u.w;
        }
        __shared__ float ls[4], lq[4];
        float s = wave_sum(sa + sb);
        float q = wave_sum(qa + qb);
        if (lane == 0) { ls[wid] = s; lq[wid] = q; }
        __syncthreads();
        if (tid == 0) {
            partials[blk * 2 + 0] = ls[0] + ls[1] + ls[2] + ls[3];
            partials[blk * 2 + 1] = lq[0] + lq[1] + lq[2] + lq[3];
        }
    } else if (blk < 576) {
        int idx = blk - 512;            // b*16+gi
        int b = idx >> 4, gi = idx & 15;
        const float* base = dec4 + (size_t)idx * 8192;
        int ch = tid >> 3, sub = tid & 7;
        const float4* r = (const float4*)(base + ch * 256 + sub * 32);
        float v[32];
        float s = 0.f, q = 0.f;
#pragma unroll
        for (int i = 0; i < 8; ++i) {
            float4 a = r[i];
            v[i * 4 + 0] = a.x; v[i * 4 + 1] = a.y; v[i * 4 + 2] = a.z; v[i * 4 + 3] = a.w;
            s += a.x + a.y + a.z + a.w;
            q += a.x * a.x + a.y * a.y + a.z * a.z + a.w * a.w;
        }
        __shared__ float ls[4], lq[4], bc[2];
        s = wave_sum(s); q = wave_sum(q);
        if (lane == 0) { ls[wid] = s; lq[wid] = q; }
        __syncthreads();
        if (tid == 0) {
            float S = ls[0] + ls[1] + ls[2] + ls[3];
            float Q = lq[0] + lq[1] + lq[2] + lq[3];
            const float inv = 1.f / 8192.f;
            float mu = S * inv;
            float var = Q * inv - mu * mu;
            bc[0] = mu;
            bc[1] = rsqrtf(var + 1e-5f);
        }
        __syncthreads();
        float mu = bc[0], rs = bc[1];
        int c = gi * 32 + ch;
        float sc = rs * gn_gap_gamma[c];
        float sh = gn_gap_beta[c] - mu * sc;
        float acc = 0.f;
#pragma unroll
        for (int i = 0; i < 32; ++i) acc += fmaxf(v[i] * sc + sh, 0.f);
#pragma unroll
        for (int m = 1; m < 8; m <<= 1) acc += __shfl_xor(acc, m, 64);
        if (sub == 0) g_buf[b * 512 + c] = acc * (1.f / 256.f);
    } else {
        int c = blk - 576;
        __shared__ float es[256];
        es[tid] = emb[c * 256 + tid];
        __syncthreads();
        if (tid < 153) {
            const float4* w4 = (const float4*)(W_ctrl + tid * 512 + 256);
            const float4* e4 = (const float4*)es;
            float acc = 0.f;
#pragma unroll 8
            for (int k = 0; k < 64; ++k) {
                float4 a = w4[k], e = e4[k];
                acc += a.x * e.x + a.y * e.y + a.z * e.z + a.w * e.w;
            }
            E_ws[c * 153 + tid] = acc;
        }
    }
}

// =============== Kernel 2: fc (4 blocks x 256) -> packed f16 params ===============
__global__ __launch_bounds__(256) void fc(
    const float* __restrict__ g_buf, const float* __restrict__ W_gap,
    const float* __restrict__ b_gap, const float* __restrict__ W_ctrl,
    const float* __restrict__ b_ctrl, const float* __restrict__ E_ws,
    unsigned char* __restrict__ pk) {
    int b = blockIdx.x, tid = threadIdx.x;
    __shared__ float gs[512];
    __shared__ float xf[256];
    __shared__ float F[160];
    gs[tid] = g_buf[b * 512 + tid];
    gs[tid + 256] = g_buf[b * 512 + 256 + tid];
    __syncthreads();
    {
        const float4* w = (const float4*)(W_gap + tid * 512);
        const float4* g4 = (const float4*)gs;
        float acc = b_gap[tid];
#pragma unroll 8
        for (int k = 0; k < 128; ++k) {
            float4 wv = w[k], gv = g4[k];
            acc += wv.x * gv.x + wv.y * gv.y + wv.z * gv.z + wv.w * gv.w;
        }
        xf[tid] = acc;
    }
    __syncthreads();
    if (tid < 160) {
        float acc = 0.f;
        if (tid < 153) {
            const float4* w = (const float4*)(W_ctrl + tid * 512);
            const float4* x4 = (const float4*)xf;
#pragma unroll 8
            for (int k = 0; k < 64; ++k) {
                float4 wv = w[k], xv = x4[k];
                acc += wv.x * xv.x + wv.y * xv.y + wv.z * xv.z + wv.w * xv.w;
            }
            acc += b_ctrl[tid];
        }
        F[tid] = acc;
    }
    __syncthreads();
    unsigned char* dst = pk + (size_t)b * 10240;
    for (int c = 0; c < 32; ++c) {
        if (tid < 152) {
            float v = F[tid] + E_ws[c * 153 + tid];
            ((__fp16*)(dst + c * 320))[tid] = (__fp16)v;
        } else if (tid == 152) {
            *(float*)(dst + c * 320 + 304) = F[152] + E_ws[c * 153 + 152];
        }
    }
}

// 8-in/8-out f16 MLP layer for one pixel
__device__ inline void layer8(const float4 W[8], const float bias[8],
                              const h2 xin[4], h2 xout[4]) {
    float t[8];
#pragma unroll
    for (int o = 0; o < 8; ++o) {
        h2 wa = __builtin_bit_cast(h2, W[o].x), wb = __builtin_bit_cast(h2, W[o].y),
           wc = __builtin_bit_cast(h2, W[o].z), wd = __builtin_bit_cast(h2, W[o].w);
        float s = dot2f(wd, xin[3], dot2f(wc, xin[2], dot2f(wb, xin[1], dot2f(wa, xin[0], bias[o]))));
        t[o] = fmaxf(s, 0.f);
    }
    xout[0] = __builtin_amdgcn_cvt_pkrtz(t[0], t[1]);
    xout[1] = __builtin_amdgcn_cvt_pkrtz(t[2], t[3]);
    xout[2] = __builtin_amdgcn_cvt_pkrtz(t[4], t[5]);
    xout[3] = __builtin_amdgcn_cvt_pkrtz(t[6], t[7]);
}

__device__ inline float layer_out(float4 w3r, float b3v, const h2 z[4]) {
    h2 wa = __builtin_bit_cast(h2, w3r.x), wb = __builtin_bit_cast(h2, w3r.y),
       wc = __builtin_bit_cast(h2, w3r.z), wd = __builtin_bit_cast(h2, w3r.w);
    return dot2f(wd, z[3], dot2f(wc, z[2], dot2f(wb, z[1], dot2f(wa, z[0], b3v))));
}

// =============== Kernel 3: mainK (1024 blocks x 512, 8 waves) ===============
// Block = (b, 256-px tile). Head: thread = (px, ch-half), LDS combine.
// MLP: wave w owns c in [4w,4w+4); per c 2 j-iters x 2 px per lane.
__global__ __launch_bounds__(512, 4) void mainK(
    const float* __restrict__ feat, const float* __restrict__ partials,
    const float* __restrict__ gamma, const float* __restrict__ beta,
    const float* __restrict__ W_pre, const float* __restrict__ b_pre,
    const float4* __restrict__ pk, float* __restrict__ out) {
    int blk = blockIdx.x;            // 0..1023
    int b = blk >> 8;
    int tid = threadIdx.x;
    int w = tid >> 6, lane = tid & 63;
    int P0 = (blk & 255) << 8;       // 256-px tile

    __shared__ __align__(16) float smem[6816];  // 27264 B -> 4 blocks/CU
    float4* pp   = (float4*)smem;               // [0,2560) packed params
    float4* tmpA = (float4*)(smem + 2560);      // [2560,4608) head partials lo
    float4* tmpB = (float4*)(smem + 4608);      // [4608,6656) head partials hi
    float4* hi_l = tmpA;                        // alias after combine (256 used)
    float2* sch  = (float2*)(smem + 6656);      // 64 x (scale, shift)
    float* mus = smem + 6784;                   // 16
    float* rss = smem + 6800;                   // 16

    const float4* src = pk + (size_t)b * 640;
    for (int i = tid; i < 640; i += 512) pp[i] = src[i];

    if (tid < 16) {
        float s = 0.f, q = 0.f;
#pragma unroll
        for (int cc = 0; cc < 8; ++cc) {
            int idx = ((b * 16 + tid) * 8 + cc) * 2;
            s += partials[idx]; q += partials[idx + 1];
        }
        const float inv = 1.f / 262144.f;
        float mu = s * inv;
        float var = q * inv - mu * mu;
        mus[tid] = mu; rss[tid] = rsqrtf(var + 1e-5f);
    }
    __syncthreads();
    if (tid < 64) {
        float mu = mus[tid >> 2], rs = rss[tid >> 2];
        float sg = rs * gamma[tid];
        sch[tid] = make_float2(sg, beta[tid] - mu * sg);
    }
    __syncthreads();

    // head: thread = (px = tid&255, half = tid>>8); 32 channels each
    {
        int px = tid & 255, half = tid >> 8;
        float hi[8];
#pragma unroll
        for (int o = 0; o < 8; ++o) hi[o] = half ? 0.f : b_pre[o];
        const float* fb = feat + ((size_t)b << 22) + ((size_t)half << 21) + P0 + px;
        const float* wp = W_pre + half * 32;
#pragma unroll
        for (int c2 = 0; c2 < 32; ++c2) {
            int ch = half * 32 + c2;
            float v = fb[(size_t)c2 << 16];
            float2 ss = sch[ch];
            float pre = fmaxf(v * ss.x + ss.y, 0.f);
#pragma unroll
            for (int o = 0; o < 8; ++o) hi[o] += wp[o * 64 + c2] * pre;
        }
        tmpA[tid] = make_float4(hi[0], hi[1], hi[2], hi[3]);
        tmpB[tid] = make_float4(hi[4], hi[5], hi[6], hi[7]);
    }
    __syncthreads();
    if (tid < 256) {
        float4 a0 = tmpA[tid], a1 = tmpA[tid + 256];
        float4 b0 = tmpB[tid], b1 = tmpB[tid + 256];
        float4 hq;
        hq.x = __builtin_bit_cast(float, __builtin_amdgcn_cvt_pkrtz(a0.x + a1.x, a0.y + a1.y));
        hq.y = __builtin_bit_cast(float, __builtin_amdgcn_cvt_pkrtz(a0.z + a1.z, a0.w + a1.w));
        hq.z = __builtin_bit_cast(float, __builtin_amdgcn_cvt_pkrtz(b0.x + b1.x, b0.y + b1.y));
        hq.w = __builtin_bit_cast(float, __builtin_amdgcn_cvt_pkrtz(b0.z + b1.z, b0.w + b1.w));
        hi_l[tid] = hq;   // aliases tmpA[tid]: same-thread RAW only
    }
    __syncthreads();

    // MLP: wave w -> c in [4w,4w+4); per c: j<2, px {j*128+lane, j*128+64+lane}
    float* ob = out + ((size_t)b << 21) + P0;
#pragma unroll 1
    for (int kk = 0; kk < 4; ++kk) {
        int c = (w << 2) + kk;
        const float4* Pc = pp + c * 20;
        float4 w1r[8], w2r[8];
#pragma unroll
        for (int o = 0; o < 8; ++o) w1r[o] = Pc[o];
#pragma unroll
        for (int o = 0; o < 8; ++o) w2r[o] = Pc[8 + o];
        float4 w3r = Pc[16];
        float4 b1r = Pc[17];
        float4 b2r = Pc[18];
        float b3v = Pc[19].x;
        float b1f[8], b2f[8];
        { h2 t = __builtin_bit_cast(h2, b1r.x); b1f[0] = t.x; b1f[1] = t.y; }
        { h2 t = __builtin_bit_cast(h2, b1r.y); b1f[2] = t.x; b1f[3] = t.y; }
        { h2 t = __builtin_bit_cast(h2, b1r.z); b1f[4] = t.x; b1f[5] = t.y; }
        { h2 t = __builtin_bit_cast(h2, b1r.w); b1f[6] = t.x; b1f[7] = t.y; }
        { h2 t = __builtin_bit_cast(h2, b2r.x); b2f[0] = t.x; b2f[1] = t.y; }
        { h2 t = __builtin_bit_cast(h2, b2r.y); b2f[2] = t.x; b2f[3] = t.y; }
        { h2 t = __builtin_bit_cast(h2, b2r.z); b2f[4] = t.x; b2f[5] = t.y; }
        { h2 t = __builtin_bit_cast(h2, b2r.w); b2f[6] = t.x; b2f[7] = t.y; }

        float* cp = ob + ((size_t)c << 16);
#pragma unroll
        for (int j = 0; j < 2; ++j) {
            int px0 = j * 128 + lane;
            int px1 = px0 + 64;
            float4 ha = hi_l[px0];
            float4 hb = hi_l[px1];
            h2 xa[4] = { __builtin_bit_cast(h2, ha.x), __builtin_bit_cast(h2, ha.y),
                         __builtin_bit_cast(h2, ha.z), __builtin_bit_cast(h2, ha.w) };
            h2 xb[4] = { __builtin_bit_cast(h2, hb.x), __builtin_bit_cast(h2, hb.y),
                         __builtin_bit_cast(h2, hb.z), __builtin_bit_cast(h2, hb.w) };
            h2 ya[4], yb[4], za[4], zb[4];
            layer8(w1r, b1f, xa, ya);
            layer8(w1r, b1f, xb, yb);
            layer8(w2r, b2f, ya, za);
            layer8(w2r, b2f, yb, zb);
            cp[px0] = layer_out(w3r, b3v, za);
            cp[px1] = layer_out(w3r, b3v, zb);
        }
    }
}

// ---------------- launch ----------------
extern "C" void kernel_launch(void* const* d_in, const int* in_sizes, int n_in,
                              void* d_out, int out_size, void* d_ws, size_t ws_size,
                              hipStream_t stream) {
    const float* dec4         = (const float*)d_in[0];
    const float* feat         = (const float*)d_in[1];
    const float* gn_pre_gamma = (const float*)d_in[2];
    const float* gn_pre_beta  = (const float*)d_in[3];
    const float* W_pre        = (const float*)d_in[4];
    const float* b_pre        = (const float*)d_in[5];
    const float* gn_gap_gamma = (const float*)d_in[6];
    const float* gn_gap_beta  = (const float*)d_in[7];
    const float* W_gap        = (const float*)d_in[8];
    const float* b_gap        = (const float*)d_in[9];
    const float* emb          = (const float*)d_in[10];
    const float* W_ctrl       = (const float*)d_in[11];
    const float* b_ctrl       = (const float*)d_in[12];
    float* out = (float*)d_out;
    float* ws  = (float*)d_ws;

    float* partials = ws;            // 1024 floats (512 x 2)
    float* g_buf    = ws + 1024;     // 2048
    float* E_ws     = ws + 3072;     // 4896
    unsigned char* pkB = (unsigned char*)(ws + 7968);  // 40960 B (16B-aligned)

    prep<<<608, 256, 0, stream>>>(feat, dec4, gn_gap_gamma, gn_gap_beta,
                                  emb, W_ctrl, partials, g_buf, E_ws);
    fc<<<4, 256, 0, stream>>>(g_buf, W_gap, b_gap, W_ctrl, b_ctrl, E_ws, pkB);
    mainK<<<1024, 512, 0, stream>>>(feat, partials, gn_pre_gamma, gn_pre_beta,
                                    W_pre, b_pre, (const float4*)pkB, out);
}

// Round 13
// 73.321 us; speedup vs baseline: 1.3322x; 1.3322x over previous
//
#include <hip/hip_runtime.h>
#include <hip/hip_fp16.h>

typedef __fp16 h2 __attribute__((ext_vector_type(2)));
typedef __fp16 v4h __attribute__((ext_vector_type(4)));
typedef float f32x4 __attribute__((ext_vector_type(4)));

__device__ inline float wave_sum(float v) {
#pragma unroll
    for (int off = 32; off > 0; off >>= 1) v += __shfl_down(v, off, 64);
    return v;
}

// relu + pack f32x4 -> f16x4 (relu done in f16 after RTZ cvt: identical for sign)
__device__ inline v4h relu_pack(f32x4 d) {
    h2 lo = __builtin_amdgcn_cvt_pkrtz(d[0], d[1]);
    h2 hi = __builtin_amdgcn_cvt_pkrtz(d[2], d[3]);
#if defined(__has_builtin)
#if __has_builtin(__builtin_elementwise_max)
    h2 z = {(__fp16)0, (__fp16)0};
    lo = __builtin_elementwise_max(lo, z);
    hi = __builtin_elementwise_max(hi, z);
#else
    lo.x = (__fp16)fmaxf((float)lo.x, 0.f); lo.y = (__fp16)fmaxf((float)lo.y, 0.f);
    hi.x = (__fp16)fmaxf((float)hi.x, 0.f); hi.y = (__fp16)fmaxf((float)hi.y, 0.f);
#endif
#endif
    v4h r = {lo.x, lo.y, hi.x, hi.y};
    return r;
}

// =============== Kernel 1: prep (608 blocks x 256) — R8 proven ===============
__global__ __launch_bounds__(256) void prep(
    const float* __restrict__ feat, const float* __restrict__ dec4,
    const float* __restrict__ gn_gap_gamma, const float* __restrict__ gn_gap_beta,
    const float* __restrict__ emb, const float* __restrict__ W_ctrl,
    float* __restrict__ partials, float* __restrict__ g_buf,
    float* __restrict__ E_ws) {
    int blk = blockIdx.x;
    int tid = threadIdx.x;
    int wid = tid >> 6, lane = tid & 63;
    if (blk < 512) {
        int grp = blk >> 3;     // b*16+g
        int chunk = blk & 7;
        const float4* base = (const float4*)(feat + (size_t)grp * 262144 + (size_t)chunk * 32768);
        float sa = 0.f, qa = 0.f, sb = 0.f, qb = 0.f;
#pragma unroll 8
        for (int i = 0; i < 16; ++i) {
            float4 v = base[i * 256 + tid];
            float4 u = base[(i + 16) * 256 + tid];
            sa += v.x + v.y + v.z + v.w;
            qa += v.x * v.x + v.y * v.y + v.z * v.z + v.w * v.w;
            sb += u.x + u.y + u.z + u.w;
            qb += u.x * u.x + u.y * u.y + u.z * u.z + u.w * u.w;
        }
        __shared__ float ls[4], lq[4];
        float s = wave_sum(sa + sb);
        float q = wave_sum(qa + qb);
        if (lane == 0) { ls[wid] = s; lq[wid] = q; }
        __syncthreads();
        if (tid == 0) {
            partials[blk * 2 + 0] = ls[0] + ls[1] + ls[2] + ls[3];
            partials[blk * 2 + 1] = lq[0] + lq[1] + lq[2] + lq[3];
        }
    } else if (blk < 576) {
        int idx = blk - 512;            // b*16+gi
        int b = idx >> 4, gi = idx & 15;
        const float* base = dec4 + (size_t)idx * 8192;
        int ch = tid >> 3, sub = tid & 7;
        const float4* r = (const float4*)(base + ch * 256 + sub * 32);
        float v[32];
        float s = 0.f, q = 0.f;
#pragma unroll
        for (int i = 0; i < 8; ++i) {
            float4 a = r[i];
            v[i * 4 + 0] = a.x; v[i * 4 + 1] = a.y; v[i * 4 + 2] = a.z; v[i * 4 + 3] = a.w;
            s += a.x + a.y + a.z + a.w;
            q += a.x * a.x + a.y * a.y + a.z * a.z + a.w * a.w;
        }
        __shared__ float ls[4], lq[4], bc[2];
        s = wave_sum(s); q = wave_sum(q);
        if (lane == 0) { ls[wid] = s; lq[wid] = q; }
        __syncthreads();
        if (tid == 0) {
            float S = ls[0] + ls[1] + ls[2] + ls[3];
            float Q = lq[0] + lq[1] + lq[2] + lq[3];
            const float inv = 1.f / 8192.f;
            float mu = S * inv;
            float var = Q * inv - mu * mu;
            bc[0] = mu;
            bc[1] = rsqrtf(var + 1e-5f);
        }
        __syncthreads();
        float mu = bc[0], rs = bc[1];
        int c = gi * 32 + ch;
        float sc = rs * gn_gap_gamma[c];
        float sh = gn_gap_beta[c] - mu * sc;
        float acc = 0.f;
#pragma unroll
        for (int i = 0; i < 32; ++i) acc += fmaxf(v[i] * sc + sh, 0.f);
#pragma unroll
        for (int m = 1; m < 8; m <<= 1) acc += __shfl_xor(acc, m, 64);
        if (sub == 0) g_buf[b * 512 + c] = acc * (1.f / 256.f);
    } else {
        int c = blk - 576;
        __shared__ float es[256];
        es[tid] = emb[c * 256 + tid];
        __syncthreads();
        if (tid < 153) {
            const float4* w4 = (const float4*)(W_ctrl + tid * 512 + 256);
            const float4* e4 = (const float4*)es;
            float acc = 0.f;
#pragma unroll 8
            for (int k = 0; k < 64; ++k) {
                float4 a = w4[k], e = e4[k];
                acc += a.x * e.x + a.y * e.y + a.z * e.z + a.w * e.w;
            }
            E_ws[c * 153 + tid] = acc;
        }
    }
}

// =============== Kernel 2: fc (4 blocks x 256) -> packed f16 params ===============
// Per (b,c), 320 B: f16[152] = W1(8x8)|W2(8x8)|W3(8)|b1(8)|b2(8); f32 b3 @304.
__global__ __launch_bounds__(256) void fc(
    const float* __restrict__ g_buf, const float* __restrict__ W_gap,
    const float* __restrict__ b_gap, const float* __restrict__ W_ctrl,
    const float* __restrict__ b_ctrl, const float* __restrict__ E_ws,
    unsigned char* __restrict__ pk) {
    int b = blockIdx.x, tid = threadIdx.x;
    __shared__ float gs[512];
    __shared__ float xf[256];
    __shared__ float F[160];
    gs[tid] = g_buf[b * 512 + tid];
    gs[tid + 256] = g_buf[b * 512 + 256 + tid];
    __syncthreads();
    {
        const float4* w = (const float4*)(W_gap + tid * 512);
        const float4* g4 = (const float4*)gs;
        float acc = b_gap[tid];
#pragma unroll 8
        for (int k = 0; k < 128; ++k) {
            float4 wv = w[k], gv = g4[k];
            acc += wv.x * gv.x + wv.y * gv.y + wv.z * gv.z + wv.w * gv.w;
        }
        xf[tid] = acc;
    }
    __syncthreads();
    if (tid < 160) {
        float acc = 0.f;
        if (tid < 153) {
            const float4* w = (const float4*)(W_ctrl + tid * 512);
            const float4* x4 = (const float4*)xf;
#pragma unroll 8
            for (int k = 0; k < 64; ++k) {
                float4 wv = w[k], xv = x4[k];
                acc += wv.x * xv.x + wv.y * xv.y + wv.z * xv.z + wv.w * xv.w;
            }
            acc += b_ctrl[tid];
        }
        F[tid] = acc;
    }
    __syncthreads();
    unsigned char* dst = pk + (size_t)b * 10240;
    for (int c = 0; c < 32; ++c) {
        if (tid < 152) {
            float v = F[tid] + E_ws[c * 153 + tid];
            ((__fp16*)(dst + c * 320))[tid] = (__fp16)v;
        } else if (tid == 152) {
            *(float*)(dst + c * 320 + 304) = F[152] + E_ws[c * 153 + 152];
        }
    }
}

// ---- per-c-pair MFMA fragments ----
struct Frags { v4h A1, A2, A3; f32x4 C1, C2, C3; };

__device__ inline Frags make_frags(const __fp16* ph, const float* smemf, int c0,
                                   int csel, int o, int dup, int crow,
                                   bool ok1, bool okBD) {
    Frags f;
    int cbA = (c0 + csel) * 160;   // __fp16 index of this row's class
    int cbB = (c0 + crow) * 160;   // class for this lane's C rows
    v4h z = {(__fp16)0, (__fp16)0, (__fp16)0, (__fp16)0};
    v4h a1 = *(const v4h*)(ph + cbA + o * 8 + dup * 4);        // W1[o][k-part]
    v4h a2 = *(const v4h*)(ph + cbA + 64 + o * 8 + dup * 4);   // W2[o][k-part]
    v4h a3 = *(const v4h*)(ph + cbA + 128 + dup * 4);          // W3[k-part]
    f.A1 = ok1 ? a1 : z;                 // layer1: rows stacked, k 0-7 only
    f.A2 = okBD ? a2 : z;                // layer2: block-diagonal
    f.A3 = (okBD && o == 0) ? a3 : z;    // layer3: rows 0 and 8 only
    v4h b1 = *(const v4h*)(ph + cbB + 136 + dup * 4);
    v4h b2 = *(const v4h*)(ph + cbB + 144 + dup * 4);
    f.C1 = f32x4{(float)b1.x, (float)b1.y, (float)b1.z, (float)b1.w};
    f.C2 = f32x4{(float)b2.x, (float)b2.y, (float)b2.z, (float)b2.w};
    f.C3 = f32x4{0.f, 0.f, 0.f, 0.f};
    if (dup == 0) f.C3[0] = smemf[(c0 + crow) * 80 + 76];      // b3 at rows 0/8
    return f;
}

// =============== Kernel 3: mainK (512 blocks x 512, 8 waves) ===============
// Block = (b, 512-px tile). Head: 1 px/thread -> hi_l[px] (8 f16).
// MLP: wave w owns c in [4w,4w+4) as two pairs; per 16-px group: 6 MFMA.
__global__ __launch_bounds__(512, 4) void mainK(
    const float* __restrict__ feat, const float* __restrict__ partials,
    const float* __restrict__ gamma, const float* __restrict__ beta,
    const float* __restrict__ W_pre, const float* __restrict__ b_pre,
    const float4* __restrict__ pk, float* __restrict__ out) {
    int blk = blockIdx.x;            // 0..511
    int b = blk >> 7;
    int tid = threadIdx.x;
    int w = tid >> 6, lane = tid & 63;
    int P0 = (blk & 127) << 9;       // 512-px tile

    __shared__ __align__(16) float smem[4768];  // 19072 B
    float4* pp   = (float4*)smem;               // [0,2560) packed params
    float4* hi_l = (float4*)(smem + 2560);      // [2560,4608) hi_l[px] f16x8
    float2* sch  = (float2*)(smem + 4608);      // 64 x (scale, shift)
    float* mus = smem + 4736;                   // 16
    float* rss = smem + 4752;                   // 16

    const float4* src = pk + (size_t)b * 640;
    for (int i = tid; i < 640; i += 512) pp[i] = src[i];

    if (tid < 16) {
        float s = 0.f, q = 0.f;
#pragma unroll
        for (int cc = 0; cc < 8; ++cc) {
            int idx = ((b * 16 + tid) * 8 + cc) * 2;
            s += partials[idx]; q += partials[idx + 1];
        }
        const float inv = 1.f / 262144.f;
        float mu = s * inv;
        float var = q * inv - mu * mu;
        mus[tid] = mu; rss[tid] = rsqrtf(var + 1e-5f);
    }
    __syncthreads();
    if (tid < 64) {
        float mu = mus[tid >> 2], rs = rss[tid >> 2];
        float sg = rs * gamma[tid];
        sch[tid] = make_float2(sg, beta[tid] - mu * sg);
    }
    __syncthreads();

    // head: 1 px per thread -> hi_l[tid] (px-direct layout)
    {
        float hi[8];
#pragma unroll
        for (int o2 = 0; o2 < 8; ++o2) hi[o2] = b_pre[o2];
        const float* fb = feat + ((size_t)b << 22) + P0 + tid;
#pragma unroll
        for (int ch = 0; ch < 64; ++ch) {
            float v = fb[(size_t)ch << 16];
            float2 ss = sch[ch];
            float pre = fmaxf(v * ss.x + ss.y, 0.f);
#pragma unroll
            for (int o2 = 0; o2 < 8; ++o2) hi[o2] += W_pre[o2 * 64 + ch] * pre;
        }
        float4 hq;
        hq.x = __builtin_bit_cast(float, __builtin_amdgcn_cvt_pkrtz(hi[0], hi[1]));
        hq.y = __builtin_bit_cast(float, __builtin_amdgcn_cvt_pkrtz(hi[2], hi[3]));
        hq.z = __builtin_bit_cast(float, __builtin_amdgcn_cvt_pkrtz(hi[4], hi[5]));
        hq.w = __builtin_bit_cast(float, __builtin_amdgcn_cvt_pkrtz(hi[6], hi[7]));
        hi_l[tid] = hq;
    }
    __syncthreads();

    // ---- MFMA MLP ----
    // Lane decomposition for 16x16x16: col/px = lane&15; k-group = lane>>4.
    const __fp16* ph = (const __fp16*)smem;
    int m = lane & 15;          // column = pixel-in-group; also A row = m
    int kg = lane >> 4;         // k chunk (4 wide)
    int csel = m >> 3;          // class of this A-row
    int o = m & 7;              // output within class
    int dup = kg & 1;           // k within the 8-wide class block
    int crow = kg >> 1;         // class of this lane's C/D rows
    bool ok1 = (kg < 2);
    bool okBD = (crow == csel);
    bool act = (dup == 0);      // lanes holding D rows 0 / 8

    int cA = w << 2;            // classes cA, cA+1
    int cB = cA + 2;            // classes cB, cB+1
    Frags fa = make_frags(ph, smem, cA, csel, o, dup, crow, ok1, okBD);
    Frags fb2 = make_frags(ph, smem, cB, csel, o, dup, crow, ok1, okBD);

    float* ob = out + ((size_t)b << 21) + P0;
    float* cpA = ob + ((size_t)(cA + crow) << 16) + m;
    float* cpB = ob + ((size_t)(cB + crow) << 16) + m;
    const __fp16* hp = ph + 5120 + m * 8 + dup * 4;   // hi_l: px*8 + k-part

#pragma unroll 4
    for (int g = 0; g < 32; ++g) {
        v4h B1 = *(const v4h*)(hp + g * 128);         // hi for px group g
        f32x4 d1a = __builtin_amdgcn_mfma_f32_16x16x16f16(fa.A1, B1, fa.C1, 0, 0, 0);
        f32x4 d1b = __builtin_amdgcn_mfma_f32_16x16x16f16(fb2.A1, B1, fb2.C1, 0, 0, 0);
        v4h p2a = relu_pack(d1a);
        v4h p2b = relu_pack(d1b);
        f32x4 d2a = __builtin_amdgcn_mfma_f32_16x16x16f16(fa.A2, p2a, fa.C2, 0, 0, 0);
        f32x4 d2b = __builtin_amdgcn_mfma_f32_16x16x16f16(fb2.A2, p2b, fb2.C2, 0, 0, 0);
        v4h p3a = relu_pack(d2a);
        v4h p3b = relu_pack(d2b);
        f32x4 d3a = __builtin_amdgcn_mfma_f32_16x16x16f16(fa.A3, p3a, fa.C3, 0, 0, 0);
        f32x4 d3b = __builtin_amdgcn_mfma_f32_16x16x16f16(fb2.A3, p3b, fb2.C3, 0, 0, 0);
        if (act) {
            cpA[g * 16] = d3a[0];
            cpB[g * 16] = d3b[0];
        }
    }
}

// ---------------- launch ----------------
extern "C" void kernel_launch(void* const* d_in, const int* in_sizes, int n_in,
                              void* d_out, int out_size, void* d_ws, size_t ws_size,
                              hipStream_t stream) {
    const float* dec4         = (const float*)d_in[0];
    const float* feat         = (const float*)d_in[1];
    const float* gn_pre_gamma = (const float*)d_in[2];
    const float* gn_pre_beta  = (const float*)d_in[3];
    const float* W_pre        = (const float*)d_in[4];
    const float* b_pre        = (const float*)d_in[5];
    const float* gn_gap_gamma = (const float*)d_in[6];
    const float* gn_gap_beta  = (const float*)d_in[7];
    const float* W_gap        = (const float*)d_in[8];
    const float* b_gap        = (const float*)d_in[9];
    const float* emb          = (const float*)d_in[10];
    const float* W_ctrl       = (const float*)d_in[11];
    const float* b_ctrl       = (const float*)d_in[12];
    float* out = (float*)d_out;
    float* ws  = (float*)d_ws;

    float* partials = ws;            // 1024 floats (512 x 2)
    float* g_buf    = ws + 1024;     // 2048
    float* E_ws     = ws + 3072;     // 4896
    unsigned char* pkB = (unsigned char*)(ws + 7968);  // 40960 B (16B-aligned)

    prep<<<608, 256, 0, stream>>>(feat, dec4, gn_gap_gamma, gn_gap_beta,
                                  emb, W_ctrl, partials, g_buf, E_ws);
    fc<<<4, 256, 0, stream>>>(g_buf, W_gap, b_gap, W_ctrl, b_ctrl, E_ws, pkB);
    mainK<<<512, 512, 0, stream>>>(feat, partials, gn_pre_gamma, gn_pre_beta,
                                   W_pre, b_pre, (const float4*)pkB, out);
}